// Round 5
// baseline (207.615 us; speedup 1.0000x reference)
//
#include <hip/hip_runtime.h>

#define EPS 1e-5f

typedef __attribute__((ext_vector_type(8))) short short8;
typedef __attribute__((ext_vector_type(4))) float float4v;

__device__ inline unsigned short f2bf(float f) {
  unsigned u = __float_as_uint(f);
  unsigned r = (u + 0x7fffu + ((u >> 16) & 1u)) >> 16;
  return (unsigned short)r;
}

// ---------------------------------------------------------------------------
// xform: fold BN scale into weights.
//  - Awt bf16 [kc(18)][mt(8)][q(4)][ml(16)][j(8)] (A-fragment-ready, e pad 128)
//  - Wc fp32 [ci(64)][co(64)] transposed compress weights * inv[co].
// ---------------------------------------------------------------------------
__global__ __launch_bounds__(256) void xform_kernel(
    const float* __restrict__ enc_w, const float* __restrict__ enc_gamma,
    const float* __restrict__ enc_var, const float* __restrict__ comp_w,
    const float* __restrict__ comp_gamma, const float* __restrict__ comp_var,
    ushort* __restrict__ Awt, float* __restrict__ Wc) {
  int u = blockIdx.x * 256 + threadIdx.x;
  if (u < 9216) {
    int kc = u >> 9, rem = u & 511;
    int mt = rem >> 6, q = (rem >> 4) & 3, ml = rem & 15;
    int e = mt * 16 + ml;
    int t = kc >> 1, h = kc & 1;
    int dy = t / 3, dx = t - dy * 3;
    float inv = (e < 100) ? enc_gamma[e] * rsqrtf(enc_var[e] + EPS) : 0.f;
    ushort o[8];
#pragma unroll
    for (int j = 0; j < 8; ++j) {
      int ci = h * 32 + q * 8 + j;
      float w = (e < 100) ? enc_w[(e * 64 + ci) * 9 + dy * 3 + dx] * inv : 0.f;
      o[j] = f2bf(w);
    }
    uint4 v;
    v.x = (uint)o[0] | ((uint)o[1] << 16);
    v.y = (uint)o[2] | ((uint)o[3] << 16);
    v.z = (uint)o[4] | ((uint)o[5] << 16);
    v.w = (uint)o[6] | ((uint)o[7] << 16);
    *reinterpret_cast<uint4*>(Awt + (size_t)u * 8) = v;
  } else if (u < 9216 + 4096) {
    int v = u - 9216;
    int co = v & 63;
    float inv = comp_gamma[co] * rsqrtf(comp_var[co] + EPS);
    Wc[v] = comp_w[co * 64 + (v >> 6)] * inv;
  }
}

__global__ void bias_kernel(
    const float* __restrict__ enc_b, const float* __restrict__ enc_gamma,
    const float* __restrict__ enc_beta, const float* __restrict__ enc_mean,
    const float* __restrict__ enc_var, const float* __restrict__ comp_gamma,
    const float* __restrict__ comp_beta, const float* __restrict__ comp_mean,
    const float* __restrict__ comp_var, float* __restrict__ bias2,
    float* __restrict__ bias_c) {
  int t = threadIdx.x;
  if (t < 128) {
    float v = 0.f;
    if (t < 100) {
      float inv = enc_gamma[t] * rsqrtf(enc_var[t] + EPS);
      v = enc_b[t] * inv + enc_beta[t] - enc_mean[t] * inv;
    }
    bias2[t] = v;
  } else if (t < 192) {
    int c = t - 128;
    float inv = comp_gamma[c] * rsqrtf(comp_var[c] + EPS);
    bias_c[c] = comp_beta[c] - comp_mean[c] * inv;
  }
}

// ---------------------------------------------------------------------------
// compress: 1x1 conv 64->64 + BN + ReLU -> Wm1t (bf16 pixel-major), and also
// emits Xb = bf16 copy of X in pixel-major [b][y][x][c] for the apply kernel.
// ---------------------------------------------------------------------------
__global__ __launch_bounds__(256) void compress_kernel(
    const float* __restrict__ X, const float* __restrict__ Wc,
    const float* __restrict__ bias_c, ushort* __restrict__ out,
    ushort* __restrict__ Xb) {
  int p = blockIdx.x * 256 + threadIdx.x;
  int b = p >> 14, rem = p & 16383;
  const float* xb = X + ((size_t)b << 20) + rem;
  float acc[64];
  uint xbf[32];
#pragma unroll
  for (int co = 0; co < 64; ++co) acc[co] = 0.f;
#pragma unroll 4
  for (int ci = 0; ci < 64; ++ci) {
    float xv = xb[(size_t)ci << 14];
    uint bv = (uint)f2bf(xv);
    if (ci & 1) xbf[ci >> 1] |= bv << 16; else xbf[ci >> 1] = bv;
    const float* wr = Wc + (ci << 6);
#pragma unroll
    for (int co = 0; co < 64; ++co) acc[co] = fmaf(wr[co], xv, acc[co]);
  }
  uint4* xdst = reinterpret_cast<uint4*>(Xb + (size_t)p * 64);
#pragma unroll
  for (int u = 0; u < 8; ++u) xdst[u] = reinterpret_cast<const uint4*>(xbf)[u];
  alignas(16) ushort o[64];
#pragma unroll
  for (int co = 0; co < 64; ++co)
    o[co] = f2bf(fmaxf(acc[co] + bias_c[co], 0.f));
  uint4* dst = reinterpret_cast<uint4*>(out + (size_t)p * 64);
  const uint4* src = reinterpret_cast<const uint4*>(o);
#pragma unroll
  for (int u = 0; u < 8; ++u) dst[u] = src[u];
}

// ---------------------------------------------------------------------------
// encode: 3x3 conv (64->100) implicit GEMM on MFMA + bias + softmax(25) +
// pixel-shuffle de-interleave + bf16 pack. 8x8 px tile per block ->
// 1024 blocks (4-6/CU). Wave w owns m-tiles {2w, 2w+1} x all 4 n-tiles;
// epilogue is single-phase (waves own disjoint e-ranges).
// ---------------------------------------------------------------------------
__global__ __launch_bounds__(256) void encode_mfma(
    const ushort* __restrict__ Wm1t, const ushort* __restrict__ Awt,
    const float* __restrict__ bias2, uint* __restrict__ Wtu) {
  __shared__ __align__(16) char smem[25600];   // stage 14400 B, wsm 25600 B
  ushort* Xt = (ushort*)smem;                  // [100 pos (10x10)][72 ci]
  const int tid = threadIdx.x;
  const int b = blockIdx.z;
  const int y0 = blockIdx.y * 8, x0 = blockIdx.x * 8;

  for (int u = tid; u < 800; u += 256) {       // 100 pos x 8 ci-groups
    int pos = u >> 3, cg = u & 7;
    int iy = pos / 10, ix = pos - iy * 10;
    int gy = y0 + iy - 1, gx = x0 + ix - 1;
    uint4 v = make_uint4(0, 0, 0, 0);
    if ((unsigned)gy < 128u && (unsigned)gx < 128u)
      v = *reinterpret_cast<const uint4*>(
          Wm1t + ((((size_t)b << 14) + (gy << 7) + gx) << 6) + cg * 8);
    *reinterpret_cast<uint4*>(&Xt[pos * 72 + cg * 8]) = v;
  }
  __syncthreads();

  const int wave = tid >> 6, lane = tid & 63;
  const int q = lane >> 4, px16 = lane & 15;

  float4v acc[2][4];
#pragma unroll
  for (int a = 0; a < 2; ++a)
#pragma unroll
    for (int n = 0; n < 4; ++n) acc[a][n] = (float4v){0.f, 0.f, 0.f, 0.f};

  const short8* Ap = reinterpret_cast<const short8*>(Awt);
#pragma unroll
  for (int kc = 0; kc < 18; ++kc) {
    const int t = kc >> 1, h = kc & 1;
    const int dy = t / 3, dx = t - dy * 3;
    short8 af[2];
#pragma unroll
    for (int a = 0; a < 2; ++a)
      af[a] = Ap[kc * 512 + (wave * 2 + a) * 64 + lane];
    short8 bfr[4];
#pragma unroll
    for (int n = 0; n < 4; ++n) {
      int p = n * 16 + px16;                  // pixel in 8x8 tile, row-major 8
      int iy = (p >> 3) + dy, ix = (p & 7) + dx;
      bfr[n] = *reinterpret_cast<const short8*>(
          &Xt[(iy * 10 + ix) * 72 + h * 32 + q * 8]);
    }
#pragma unroll
    for (int a = 0; a < 2; ++a)
#pragma unroll
      for (int n = 0; n < 4; ++n)
        acc[a][n] = __builtin_amdgcn_mfma_f32_16x16x32_bf16(
            af[a], bfr[n], acc[a][n], 0, 0, 0);
  }
  __syncthreads();

  // single-phase epilogue: wave w writes e in [32w, 32w+32) (guarded <100)
  float* wsm = (float*)smem;                   // [64 px][100 e]
#pragma unroll
  for (int a = 0; a < 2; ++a) {
    int ebase = (wave * 2 + a) * 16 + q * 4;
    if (ebase < 100) {
#pragma unroll
      for (int n = 0; n < 4; ++n) {
        int p = n * 16 + px16;
        *reinterpret_cast<float4v*>(wsm + p * 100 + ebase) = acc[a][n];
      }
    }
  }
  __syncthreads();

  if (tid < 64) {
    const float4v* bias4 = (const float4v*)bias2;
    float4v v[25];
    const float* wp = wsm + tid * 100;
#pragma unroll
    for (int j = 0; j < 25; ++j)
      v[j] = *reinterpret_cast<const float4v*>(wp + 4 * j) + bias4[j];
    float4v m = v[0];
#pragma unroll
    for (int j = 1; j < 25; ++j) {
      m.x = fmaxf(m.x, v[j].x); m.y = fmaxf(m.y, v[j].y);
      m.z = fmaxf(m.z, v[j].z); m.w = fmaxf(m.w, v[j].w);
    }
    float4v s = (float4v){0.f, 0.f, 0.f, 0.f};
#pragma unroll
    for (int j = 0; j < 25; ++j) {
      v[j].x = __expf(v[j].x - m.x); v[j].y = __expf(v[j].y - m.y);
      v[j].z = __expf(v[j].z - m.z); v[j].w = __expf(v[j].w - m.w);
      s += v[j];
    }
    float i0 = 1.f / s.x, i1 = 1.f / s.y, i2 = 1.f / s.z, i3 = 1.f / s.w;
    alignas(16) uint wp56[56];
#pragma unroll
    for (int k = 0; k < 25; ++k) {
      wp56[k]      = (uint)f2bf(v[k].x * i0) | ((uint)f2bf(v[k].y * i1) << 16);
      wp56[28 + k] = (uint)f2bf(v[k].z * i2) | ((uint)f2bf(v[k].w * i3) << 16);
    }
#pragma unroll
    for (int k = 25; k < 28; ++k) { wp56[k] = 0; wp56[28 + k] = 0; }
    int pix = b * 16384 + (y0 + (tid >> 3)) * 128 + x0 + (tid & 7);
    uint4* dst = reinterpret_cast<uint4*>(Wtu + (size_t)pix * 56);
#pragma unroll
    for (int j = 0; j < 14; ++j) dst[j] = reinterpret_cast<const uint4*>(wp56)[j];
  }
}

// ---------------------------------------------------------------------------
// carafe: apply only. 8x8 low-res tile per block. X staged as bf16
// [144 pos][72 ch] (20.7 KB LDS) from pixel-major Xb -> coalesced stage,
// conflict-free b128 reads, 4 reads/tap (8 ch each, unpacked to fp32).
// ---------------------------------------------------------------------------
__global__ __launch_bounds__(256) void carafe_kernel(
    const ushort* __restrict__ Xb, const uint* __restrict__ Wtu,
    float* __restrict__ out) {
  const int tid = threadIdx.x;
  const int b = blockIdx.z;
  const int y0 = blockIdx.y * 8, x0 = blockIdx.x * 8;
  __shared__ __align__(16) ushort xt[144 * 72];

  for (int u = tid; u < 1152; u += 256) {      // 144 pos x 8 ch-groups
    int pos = u >> 3, cg = u & 7;
    int iy = pos / 12, ix = pos - iy * 12;
    int gy = y0 + iy - 2, gx = x0 + ix - 2;
    uint4 v = make_uint4(0, 0, 0, 0);
    if ((unsigned)gy < 128u && (unsigned)gx < 128u)
      v = *reinterpret_cast<const uint4*>(
          Xb + (((size_t)b * 16384 + gy * 128 + gx) << 6) + cg * 8);
    *reinterpret_cast<uint4*>(&xt[pos * 72 + cg * 8]) = v;
  }
  __syncthreads();

  const int p = tid & 63, q = tid >> 6;
  const int r1 = q & 1, cq = q >> 1;
  const int py = p >> 3, px = p & 7;

  int pix = b * 16384 + (y0 + py) * 128 + (x0 + px);
  const uint4* wq = reinterpret_cast<const uint4*>(Wtu + (size_t)pix * 56 + r1 * 28);
  alignas(16) uint w[28];
#pragma unroll
  for (int j = 0; j < 7; ++j) reinterpret_cast<uint4*>(w)[j] = wq[j];

  float2 acc[32];
#pragma unroll
  for (int i = 0; i < 32; ++i) acc[i] = make_float2(0.f, 0.f);

#pragma unroll
  for (int k = 0; k < 25; ++k) {
    const int dy = k / 5, dx = k - dy * 5;
    const ushort* bp = xt + ((py + dy) * 12 + (px + dx)) * 72 + cq * 32;
    float w0 = __uint_as_float(w[k] << 16);
    float w1 = __uint_as_float(w[k] & 0xffff0000u);
#pragma unroll
    for (int j = 0; j < 4; ++j) {
      uint4 xv = *reinterpret_cast<const uint4*>(bp + 8 * j);
      const uint xu[4] = {xv.x, xv.y, xv.z, xv.w};
#pragma unroll
      for (int t = 0; t < 4; ++t) {
        float xlo = __uint_as_float(xu[t] << 16);
        float xhi = __uint_as_float(xu[t] & 0xffff0000u);
        int c = j * 8 + t * 2;
        acc[c].x = fmaf(w0, xlo, acc[c].x);
        acc[c].y = fmaf(w1, xlo, acc[c].y);
        acc[c + 1].x = fmaf(w0, xhi, acc[c + 1].x);
        acc[c + 1].y = fmaf(w1, xhi, acc[c + 1].y);
      }
    }
  }

  int yq = (y0 + py) * 2 + r1;
  int xq = (x0 + px) * 2;
#pragma unroll
  for (int ci = 0; ci < 32; ++ci) {
    int c = cq * 32 + ci;
    *reinterpret_cast<float2*>(
        out + ((size_t)(b * 64 + c) * 256 + yq) * 256 + xq) = acc[ci];
  }
}

// ---------------------------------------------------------------------------
extern "C" void kernel_launch(void* const* d_in, const int* in_sizes, int n_in,
                              void* d_out, int out_size, void* d_ws, size_t ws_size,
                              hipStream_t stream) {
  const float* X          = (const float*)d_in[0];
  const float* comp_w     = (const float*)d_in[1];
  const float* comp_gamma = (const float*)d_in[2];
  const float* comp_beta  = (const float*)d_in[3];
  const float* comp_mean  = (const float*)d_in[4];
  const float* comp_var   = (const float*)d_in[5];
  const float* enc_w      = (const float*)d_in[6];
  const float* enc_b      = (const float*)d_in[7];
  const float* enc_gamma  = (const float*)d_in[8];
  const float* enc_beta   = (const float*)d_in[9];
  const float* enc_mean   = (const float*)d_in[10];
  const float* enc_var    = (const float*)d_in[11];
  float* out = (float*)d_out;

  char* ws = (char*)d_ws;
  ushort* Wm1t  = (ushort*)(ws);                    //  8,388,608 B
  uint*   Wtu   = (uint*)(ws + 8388608);            // 14,680,064 B
  ushort* Xb    = (ushort*)(ws + 23068672);         //  8,388,608 B
  ushort* Awt   = (ushort*)(ws + 31457280);         //    147,456 B
  float*  Wc    = (float*)(ws + 31604736);          //     16,384 B
  float*  bias2 = (float*)(ws + 31621120);          //        512 B
  float*  biasc = (float*)(ws + 31621632);          //        256 B

  xform_kernel<<<52, 256, 0, stream>>>(enc_w, enc_gamma, enc_var,
                                       comp_w, comp_gamma, comp_var, Awt, Wc);
  bias_kernel<<<1, 256, 0, stream>>>(enc_b, enc_gamma, enc_beta, enc_mean,
                                     enc_var, comp_gamma, comp_beta, comp_mean,
                                     comp_var, bias2, biasc);
  compress_kernel<<<256, 256, 0, stream>>>(X, Wc, biasc, Wm1t, Xb);
  encode_mfma<<<dim3(16, 16, 4), 256, 0, stream>>>(Wm1t, Awt, bias2, Wtu);
  carafe_kernel<<<dim3(16, 16, 4), 256, 0, stream>>>(Xb, Wtu, out);
}

// Round 6
// 149.434 us; speedup vs baseline: 1.3893x; 1.3893x over previous
//
#include <hip/hip_runtime.h>

#define EPS 1e-5f

typedef __attribute__((ext_vector_type(8))) short short8;
typedef __attribute__((ext_vector_type(4))) float float4v;

__device__ inline unsigned short f2bf(float f) {
  unsigned u = __float_as_uint(f);
  unsigned r = (u + 0x7fffu + ((u >> 16) & 1u)) >> 16;
  return (unsigned short)r;
}
__device__ inline uint pk2(float a, float b) {
  return (uint)f2bf(a) | ((uint)f2bf(b) << 16);
}

// ---------------------------------------------------------------------------
// xform: fold BN scale into weights.
//  - Awt bf16 [kc(18)][mt(8)][q(4)][ml(16)][j(8)] (A-fragment-ready, e pad 128)
//  - Wc fp32 [ci(64)][co(64)] transposed compress weights * inv[co].
// ---------------------------------------------------------------------------
__global__ __launch_bounds__(256) void xform_kernel(
    const float* __restrict__ enc_w, const float* __restrict__ enc_gamma,
    const float* __restrict__ enc_var, const float* __restrict__ comp_w,
    const float* __restrict__ comp_gamma, const float* __restrict__ comp_var,
    ushort* __restrict__ Awt, float* __restrict__ Wc) {
  int u = blockIdx.x * 256 + threadIdx.x;
  if (u < 9216) {
    int kc = u >> 9, rem = u & 511;
    int mt = rem >> 6, q = (rem >> 4) & 3, ml = rem & 15;
    int e = mt * 16 + ml;
    int t = kc >> 1, h = kc & 1;
    int dy = t / 3, dx = t - dy * 3;
    float inv = (e < 100) ? enc_gamma[e] * rsqrtf(enc_var[e] + EPS) : 0.f;
    ushort o[8];
#pragma unroll
    for (int j = 0; j < 8; ++j) {
      int ci = h * 32 + q * 8 + j;
      float w = (e < 100) ? enc_w[(e * 64 + ci) * 9 + dy * 3 + dx] * inv : 0.f;
      o[j] = f2bf(w);
    }
    uint4 v;
    v.x = (uint)o[0] | ((uint)o[1] << 16);
    v.y = (uint)o[2] | ((uint)o[3] << 16);
    v.z = (uint)o[4] | ((uint)o[5] << 16);
    v.w = (uint)o[6] | ((uint)o[7] << 16);
    *reinterpret_cast<uint4*>(Awt + (size_t)u * 8) = v;
  } else if (u < 9216 + 4096) {
    int v = u - 9216;
    int co = v & 63;
    float inv = comp_gamma[co] * rsqrtf(comp_var[co] + EPS);
    Wc[v] = comp_w[co * 64 + (v >> 6)] * inv;
  }
}

__global__ void bias_kernel(
    const float* __restrict__ enc_b, const float* __restrict__ enc_gamma,
    const float* __restrict__ enc_beta, const float* __restrict__ enc_mean,
    const float* __restrict__ enc_var, const float* __restrict__ comp_gamma,
    const float* __restrict__ comp_beta, const float* __restrict__ comp_mean,
    const float* __restrict__ comp_var, float* __restrict__ bias2,
    float* __restrict__ bias_c) {
  int t = threadIdx.x;
  if (t < 128) {
    float v = 0.f;
    if (t < 100) {
      float inv = enc_gamma[t] * rsqrtf(enc_var[t] + EPS);
      v = enc_b[t] * inv + enc_beta[t] - enc_mean[t] * inv;
    }
    bias2[t] = v;
  } else if (t < 192) {
    int c = t - 128;
    float inv = comp_gamma[c] * rsqrtf(comp_var[c] + EPS);
    bias_c[c] = comp_beta[c] - comp_mean[c] * inv;
  }
}

// ---------------------------------------------------------------------------
// compress v2: 1x1 conv 64->64 + BN + ReLU -> Wm1t bf16 pixel-major, plus
// Xb bf16 pixel-major. Block = 64 consecutive pixels, 1024 blocks (4/CU).
// X staged in LDS [64px][65] (conflict-free in & out). Wave w computes
// co=[16w,16w+16) for its lane's pixel; weight/bias addresses are forced
// wave-uniform via readfirstlane -> s_load (scalar pipe). Both outputs
// bounce through LDS and leave as fully-coalesced uint4 streams.
// ---------------------------------------------------------------------------
__global__ __launch_bounds__(256) void compress_kernel(
    const float* __restrict__ X, const float* __restrict__ Wc,
    const float* __restrict__ bias_c, ushort* __restrict__ out,
    ushort* __restrict__ Xb) {
  __shared__ __align__(16) float xtile[64 * 65];
  __shared__ __align__(16) float osm[64 * 68];
  const int tid = threadIdx.x;
  const int p0 = blockIdx.x * 64;
  const int b = p0 >> 14;
  const float* xbase = X + ((size_t)b << 20) + (p0 & 16383);

#pragma unroll
  for (int k = 0; k < 16; ++k) {
    int u = k * 256 + tid;
    int ci = u >> 6, px = u & 63;      // wave: ci fixed, px 0..63 -> coalesced
    xtile[px * 65 + ci] = xbase[((size_t)ci << 14) + px];
  }
  __syncthreads();

  const int wv = __builtin_amdgcn_readfirstlane(tid >> 6);
  const int ln = tid & 63;
  float acc[16];
#pragma unroll
  for (int u = 0; u < 16; ++u) acc[u] = bias_c[wv * 16 + u];
  const float* xr = xtile + ln * 65;
#pragma unroll 8
  for (int ci = 0; ci < 64; ++ci) {
    float xv = xr[ci];
    const float* wr = Wc + ci * 64 + wv * 16;   // wave-uniform -> s_load
#pragma unroll
    for (int u = 0; u < 16; ++u) acc[u] = fmaf(wr[u], xv, acc[u]);
  }
  float4v* orow = reinterpret_cast<float4v*>(osm) + ln * 17 + wv * 4;
#pragma unroll
  for (int j = 0; j < 4; ++j) {
    float4v t;
#pragma unroll
    for (int s = 0; s < 4; ++s) t[s] = fmaxf(acc[j * 4 + s], 0.f);
    orow[j] = t;                        // stride-17 float4 -> conflict-free
  }
  __syncthreads();

#pragma unroll
  for (int j = 0; j < 2; ++j) {
    int u = j * 256 + tid;
    int px = u >> 3, g = u & 7;
    const float* so = osm + px * 68 + g * 8;
    uint4 vo = make_uint4(pk2(so[0], so[1]), pk2(so[2], so[3]),
                          pk2(so[4], so[5]), pk2(so[6], so[7]));
    *reinterpret_cast<uint4*>(out + (size_t)(p0 + px) * 64 + g * 8) = vo;
    const float* sx = xtile + px * 65 + g * 8;
    uint4 vx = make_uint4(pk2(sx[0], sx[1]), pk2(sx[2], sx[3]),
                          pk2(sx[4], sx[5]), pk2(sx[6], sx[7]));
    *reinterpret_cast<uint4*>(Xb + (size_t)(p0 + px) * 64 + g * 8) = vx;
  }
}

// ---------------------------------------------------------------------------
// encode: 3x3 conv (64->100) implicit GEMM on MFMA + bias + softmax(25) +
// pixel-shuffle de-interleave + bf16 pack. 8x8 px tile per block ->
// 1024 blocks. Wave w owns m-tiles {2w,2w+1} x all 4 n-tiles.
// ---------------------------------------------------------------------------
__global__ __launch_bounds__(256) void encode_mfma(
    const ushort* __restrict__ Wm1t, const ushort* __restrict__ Awt,
    const float* __restrict__ bias2, uint* __restrict__ Wtu) {
  __shared__ __align__(16) char smem[25600];   // stage 14400 B, wsm 25600 B
  ushort* Xt = (ushort*)smem;                  // [100 pos (10x10)][72 ci]
  const int tid = threadIdx.x;
  const int b = blockIdx.z;
  const int y0 = blockIdx.y * 8, x0 = blockIdx.x * 8;

  for (int u = tid; u < 800; u += 256) {       // 100 pos x 8 ci-groups
    int pos = u >> 3, cg = u & 7;
    int iy = pos / 10, ix = pos - iy * 10;
    int gy = y0 + iy - 1, gx = x0 + ix - 1;
    uint4 v = make_uint4(0, 0, 0, 0);
    if ((unsigned)gy < 128u && (unsigned)gx < 128u)
      v = *reinterpret_cast<const uint4*>(
          Wm1t + ((((size_t)b << 14) + (gy << 7) + gx) << 6) + cg * 8);
    *reinterpret_cast<uint4*>(&Xt[pos * 72 + cg * 8]) = v;
  }
  __syncthreads();

  const int wave = tid >> 6, lane = tid & 63;
  const int q = lane >> 4, px16 = lane & 15;

  float4v acc[2][4];
#pragma unroll
  for (int a = 0; a < 2; ++a)
#pragma unroll
    for (int n = 0; n < 4; ++n) acc[a][n] = (float4v){0.f, 0.f, 0.f, 0.f};

  const short8* Ap = reinterpret_cast<const short8*>(Awt);
#pragma unroll
  for (int kc = 0; kc < 18; ++kc) {
    const int t = kc >> 1, h = kc & 1;
    const int dy = t / 3, dx = t - dy * 3;
    short8 af[2];
#pragma unroll
    for (int a = 0; a < 2; ++a)
      af[a] = Ap[kc * 512 + (wave * 2 + a) * 64 + lane];
    short8 bfr[4];
#pragma unroll
    for (int n = 0; n < 4; ++n) {
      int p = n * 16 + px16;                  // pixel in 8x8 tile, row-major 8
      int iy = (p >> 3) + dy, ix = (p & 7) + dx;
      bfr[n] = *reinterpret_cast<const short8*>(
          &Xt[(iy * 10 + ix) * 72 + h * 32 + q * 8]);
    }
#pragma unroll
    for (int a = 0; a < 2; ++a)
#pragma unroll
      for (int n = 0; n < 4; ++n)
        acc[a][n] = __builtin_amdgcn_mfma_f32_16x16x32_bf16(
            af[a], bfr[n], acc[a][n], 0, 0, 0);
  }
  __syncthreads();

  // single-phase epilogue: wave w writes e in [32w, 32w+32) (guarded <100)
  float* wsm = (float*)smem;                   // [64 px][100 e]
#pragma unroll
  for (int a = 0; a < 2; ++a) {
    int ebase = (wave * 2 + a) * 16 + q * 4;
    if (ebase < 100) {
#pragma unroll
      for (int n = 0; n < 4; ++n) {
        int p = n * 16 + px16;
        *reinterpret_cast<float4v*>(wsm + p * 100 + ebase) = acc[a][n];
      }
    }
  }
  __syncthreads();

  if (tid < 64) {
    const float4v* bias4 = (const float4v*)bias2;
    float4v v[25];
    const float* wp = wsm + tid * 100;
#pragma unroll
    for (int j = 0; j < 25; ++j)
      v[j] = *reinterpret_cast<const float4v*>(wp + 4 * j) + bias4[j];
    float4v m = v[0];
#pragma unroll
    for (int j = 1; j < 25; ++j) {
      m.x = fmaxf(m.x, v[j].x); m.y = fmaxf(m.y, v[j].y);
      m.z = fmaxf(m.z, v[j].z); m.w = fmaxf(m.w, v[j].w);
    }
    float4v s = (float4v){0.f, 0.f, 0.f, 0.f};
#pragma unroll
    for (int j = 0; j < 25; ++j) {
      v[j].x = __expf(v[j].x - m.x); v[j].y = __expf(v[j].y - m.y);
      v[j].z = __expf(v[j].z - m.z); v[j].w = __expf(v[j].w - m.w);
      s += v[j];
    }
    float i0 = 1.f / s.x, i1 = 1.f / s.y, i2 = 1.f / s.z, i3 = 1.f / s.w;
    alignas(16) uint wp56[56];
#pragma unroll
    for (int k = 0; k < 25; ++k) {
      wp56[k]      = (uint)f2bf(v[k].x * i0) | ((uint)f2bf(v[k].y * i1) << 16);
      wp56[28 + k] = (uint)f2bf(v[k].z * i2) | ((uint)f2bf(v[k].w * i3) << 16);
    }
#pragma unroll
    for (int k = 25; k < 28; ++k) { wp56[k] = 0; wp56[28 + k] = 0; }
    int pix = b * 16384 + (y0 + (tid >> 3)) * 128 + x0 + (tid & 7);
    uint4* dst = reinterpret_cast<uint4*>(Wtu + (size_t)pix * 56);
#pragma unroll
    for (int j = 0; j < 14; ++j) dst[j] = reinterpret_cast<const uint4*>(wp56)[j];
  }
}

// ---------------------------------------------------------------------------
// carafe: apply only. 8x8 low-res tile per block. X staged as bf16
// [144 pos][72 ch] (20.7 KB LDS) from pixel-major Xb -> coalesced stage,
// conflict-free b128 reads, 4 reads/tap (8 ch each, unpacked to fp32).
// ---------------------------------------------------------------------------
__global__ __launch_bounds__(256) void carafe_kernel(
    const ushort* __restrict__ Xb, const uint* __restrict__ Wtu,
    float* __restrict__ out) {
  const int tid = threadIdx.x;
  const int b = blockIdx.z;
  const int y0 = blockIdx.y * 8, x0 = blockIdx.x * 8;
  __shared__ __align__(16) ushort xt[144 * 72];

  for (int u = tid; u < 1152; u += 256) {      // 144 pos x 8 ch-groups
    int pos = u >> 3, cg = u & 7;
    int iy = pos / 12, ix = pos - iy * 12;
    int gy = y0 + iy - 2, gx = x0 + ix - 2;
    uint4 v = make_uint4(0, 0, 0, 0);
    if ((unsigned)gy < 128u && (unsigned)gx < 128u)
      v = *reinterpret_cast<const uint4*>(
          Xb + (((size_t)b * 16384 + gy * 128 + gx) << 6) + cg * 8);
    *reinterpret_cast<uint4*>(&xt[pos * 72 + cg * 8]) = v;
  }
  __syncthreads();

  const int p = tid & 63, q = tid >> 6;
  const int r1 = q & 1, cq = q >> 1;
  const int py = p >> 3, px = p & 7;

  int pix = b * 16384 + (y0 + py) * 128 + (x0 + px);
  const uint4* wq = reinterpret_cast<const uint4*>(Wtu + (size_t)pix * 56 + r1 * 28);
  alignas(16) uint w[28];
#pragma unroll
  for (int j = 0; j < 7; ++j) reinterpret_cast<uint4*>(w)[j] = wq[j];

  float2 acc[32];
#pragma unroll
  for (int i = 0; i < 32; ++i) acc[i] = make_float2(0.f, 0.f);

#pragma unroll
  for (int k = 0; k < 25; ++k) {
    const int dy = k / 5, dx = k - dy * 5;
    const ushort* bp = xt + ((py + dy) * 12 + (px + dx)) * 72 + cq * 32;
    float w0 = __uint_as_float(w[k] << 16);
    float w1 = __uint_as_float(w[k] & 0xffff0000u);
#pragma unroll
    for (int j = 0; j < 4; ++j) {
      uint4 xv = *reinterpret_cast<const uint4*>(bp + 8 * j);
      const uint xu[4] = {xv.x, xv.y, xv.z, xv.w};
#pragma unroll
      for (int t = 0; t < 4; ++t) {
        float xlo = __uint_as_float(xu[t] << 16);
        float xhi = __uint_as_float(xu[t] & 0xffff0000u);
        int c = j * 8 + t * 2;
        acc[c].x = fmaf(w0, xlo, acc[c].x);
        acc[c].y = fmaf(w1, xlo, acc[c].y);
        acc[c + 1].x = fmaf(w0, xhi, acc[c + 1].x);
        acc[c + 1].y = fmaf(w1, xhi, acc[c + 1].y);
      }
    }
  }

  int yq = (y0 + py) * 2 + r1;
  int xq = (x0 + px) * 2;
#pragma unroll
  for (int ci = 0; ci < 32; ++ci) {
    int c = cq * 32 + ci;
    *reinterpret_cast<float2*>(
        out + ((size_t)(b * 64 + c) * 256 + yq) * 256 + xq) = acc[ci];
  }
}

// ---------------------------------------------------------------------------
extern "C" void kernel_launch(void* const* d_in, const int* in_sizes, int n_in,
                              void* d_out, int out_size, void* d_ws, size_t ws_size,
                              hipStream_t stream) {
  const float* X          = (const float*)d_in[0];
  const float* comp_w     = (const float*)d_in[1];
  const float* comp_gamma = (const float*)d_in[2];
  const float* comp_beta  = (const float*)d_in[3];
  const float* comp_mean  = (const float*)d_in[4];
  const float* comp_var   = (const float*)d_in[5];
  const float* enc_w      = (const float*)d_in[6];
  const float* enc_b      = (const float*)d_in[7];
  const float* enc_gamma  = (const float*)d_in[8];
  const float* enc_beta   = (const float*)d_in[9];
  const float* enc_mean   = (const float*)d_in[10];
  const float* enc_var    = (const float*)d_in[11];
  float* out = (float*)d_out;

  char* ws = (char*)d_ws;
  ushort* Wm1t  = (ushort*)(ws);                    //  8,388,608 B
  uint*   Wtu   = (uint*)(ws + 8388608);            // 14,680,064 B
  ushort* Xb    = (ushort*)(ws + 23068672);         //  8,388,608 B
  ushort* Awt   = (ushort*)(ws + 31457280);         //    147,456 B
  float*  Wc    = (float*)(ws + 31604736);          //     16,384 B
  float*  bias2 = (float*)(ws + 31621120);          //        512 B
  float*  biasc = (float*)(ws + 31621632);          //        256 B

  xform_kernel<<<52, 256, 0, stream>>>(enc_w, enc_gamma, enc_var,
                                       comp_w, comp_gamma, comp_var, Awt, Wc);
  bias_kernel<<<1, 256, 0, stream>>>(enc_b, enc_gamma, enc_beta, enc_mean,
                                     enc_var, comp_gamma, comp_beta, comp_mean,
                                     comp_var, bias2, biasc);
  compress_kernel<<<1024, 256, 0, stream>>>(X, Wc, biasc, Wm1t, Xb);
  encode_mfma<<<dim3(16, 16, 4), 256, 0, stream>>>(Wm1t, Awt, bias2, Wtu);
  carafe_kernel<<<dim3(16, 16, 4), 256, 0, stream>>>(Xb, Wtu, out);
}